// Round 1
// baseline (169.238 us; speedup 1.0000x reference)
//
#include <hip/hip_runtime.h>
#include <hip/hip_fp16.h>

// Problem constants (from reference)
#define DIMS   10000
#define LEVELS 100
#define SSIZE  617
#define NCLS   26
#define BATCH  32

// Tiling
#define DTILE 256                 // dims per block (64 lanes x 4 dims)
#define TILE_PITCH_B (DTILE * 2)  // bytes per level row in LDS (fp16) = 512
#define MAXCHUNK 8

// ws layout: [0, 78976) int32 offsets off[s][b] = idx*512 ; part at 128 KiB
#define PART_OFF (128 * 1024)

// ---------------------------------------------------------------------------
// K1: quantize x -> level indices, pre-scaled to LDS byte offsets, stored
// TRANSPOSED off[s][b] so 8 consecutive b for fixed s merge into one
// s_load_dwordx8 in K2's inner loop. Also zero-init d_out (poisoned 0xAA).
// ---------------------------------------------------------------------------
__global__ __launch_bounds__(256) void k_prep(const float* __restrict__ x,
                                              int* __restrict__ offb,
                                              float* __restrict__ out)
{
    int tid = blockIdx.x * 256 + threadIdx.x;
    if (tid < BATCH * SSIZE) {
        int b = tid / SSIZE;
        int s = tid - b * SSIZE;
        float v = x[tid];                       // x[b][s]
        float r = rintf(v * (float)(LEVELS - 1)); // RTE, matches jnp.round
        int q = (int)r;
        q = q < 0 ? 0 : (q > LEVELS - 1 ? LEVELS - 1 : q);
        offb[s * BATCH + b] = q * TILE_PITCH_B;
    }
    if (tid < BATCH * NCLS) out[tid] = 0.0f;
}

// ---------------------------------------------------------------------------
// K2: bind + multiset partial sums.
// Block: 256 threads = 4 waves. All waves cover the same 256-dim range
// (lane -> 4 dims); each wave owns 8 batches (template const so the idx
// offset loads stay wave-uniform -> scalar loads).
// Level tile (100 rows x 256 dims, packed fp16) staged in LDS (50 KB).
// fp16 accumulation is exact: products are +-1, |sum| <= 617 < 2048.
// ---------------------------------------------------------------------------
template <int B0>
__device__ __forceinline__ void inner_loop(const float* __restrict__ id_w,
                                           const int* __restrict__ offb,
                                           const unsigned int* tile,
                                           __half* __restrict__ part,
                                           int d0, int lane, int chunk,
                                           int sBeg, int sEnd)
{
    const int dd = d0 + lane * 4;
    const bool valid = dd < DIMS;             // DIMS % 4 == 0 -> all-or-none
    const __half2 z = __float2half2_rn(0.0f);
    __half2 a0[8], a1[8];
#pragma unroll
    for (int b = 0; b < 8; ++b) { a0[b] = z; a1[b] = z; }

    for (int s = sBeg; s < sEnd; ++s) {
        float4 iv = make_float4(0.f, 0.f, 0.f, 0.f);
        if (valid) iv = *(const float4*)(id_w + (size_t)s * DIMS + dd);
        __half2 p0 = __float22half2_rn(make_float2(iv.x, iv.y));
        __half2 p1 = __float22half2_rn(make_float2(iv.z, iv.w));
        const int* orow = offb + s * BATCH + B0;   // uniform -> s_load
#pragma unroll
        for (int b = 0; b < 8; ++b) {
            int o = orow[b];                       // scalar (uniform) load
            const __half2* lp =
                (const __half2*)((const char*)tile + o + lane * 8);
            a0[b] = __hfma2(p0, lp[0], a0[b]);     // merges to ds_read_b64
            a1[b] = __hfma2(p1, lp[1], a1[b]);
        }
    }
    if (valid) {
#pragma unroll
        for (int b = 0; b < 8; ++b) {
            unsigned long long u =
                (unsigned long long)__builtin_bit_cast(unsigned int, a0[b]) |
                ((unsigned long long)__builtin_bit_cast(unsigned int, a1[b]) << 32);
            *(unsigned long long*)((char*)part +
                ((size_t)(chunk * BATCH + B0 + b) * DIMS + dd) * 2) = u;
        }
    }
}

__global__ __launch_bounds__(256) void k_bind(const float* __restrict__ id_w,
                                              const float* __restrict__ lvl_w,
                                              const int* __restrict__ offb,
                                              __half* __restrict__ part,
                                              int sPer)
{
    __shared__ unsigned int tile[LEVELS * (DTILE / 2)];  // 100*128 u32 = 50 KB
    const int d0 = blockIdx.x * DTILE;
    const int chunk = blockIdx.y;
    const int tid = threadIdx.x;

    // Stage level tile, converting fp32 -> packed fp16 on the fly.
    for (int t = tid; t < LEVELS * (DTILE / 2); t += 256) {
        int r = t >> 7;            // /128
        int j = t & 127;
        int d = d0 + 2 * j;
        int dc = d < DIMS ? d : 0; // clamp (values unused for invalid dims)
        float2 v = *(const float2*)(lvl_w + (size_t)r * DIMS + dc);
        __half2 h = __float22half2_rn(v);
        tile[t] = __builtin_bit_cast(unsigned int, h);
    }
    __syncthreads();

    const int wave = tid >> 6;
    const int lane = tid & 63;
    const int sBeg = chunk * sPer;
    const int sEnd = min(SSIZE, sBeg + sPer);

    switch (wave) {
        case 0: inner_loop<0 >(id_w, offb, tile, part, d0, lane, chunk, sBeg, sEnd); break;
        case 1: inner_loop<8 >(id_w, offb, tile, part, d0, lane, chunk, sBeg, sEnd); break;
        case 2: inner_loop<16>(id_w, offb, tile, part, d0, lane, chunk, sBeg, sEnd); break;
        case 3: inner_loop<24>(id_w, offb, tile, part, d0, lane, chunk, sBeg, sEnd); break;
    }
}

// ---------------------------------------------------------------------------
// K3: reduce chunk partials, hard-quantize (sum of 617 odd +-1 terms is never
// 0, so no tie case), then logit[b][c] += enc . W[c]. Grid (32 b, 5 d-splits),
// wave-shuffle reduction, atomicAdd into the zeroed output.
// ---------------------------------------------------------------------------
__global__ __launch_bounds__(256) void k_logit(const __half* __restrict__ part,
                                               const float* __restrict__ W,
                                               float* __restrict__ out,
                                               int nch)
{
    const int b = blockIdx.x;
    const int tid = threadIdx.x;
    const int dBeg = blockIdx.y * 2000;

    float acc[NCLS];
#pragma unroll
    for (int c = 0; c < NCLS; ++c) acc[c] = 0.0f;

    for (int d = dBeg + tid; d < dBeg + 2000; d += 256) {
        float m = 0.0f;
        for (int c = 0; c < nch; ++c)
            m += __half2float(part[(size_t)(c * BATCH + b) * DIMS + d]);
        float e = m > 0.0f ? 1.0f : -1.0f;
#pragma unroll
        for (int c = 0; c < NCLS; ++c)
            acc[c] = fmaf(e, W[(size_t)c * DIMS + d], acc[c]);
    }

#pragma unroll
    for (int c = 0; c < NCLS; ++c) {
#pragma unroll
        for (int o = 32; o > 0; o >>= 1)
            acc[c] += __shfl_down(acc[c], o);
    }

    __shared__ float red[4][NCLS];
    const int lane = tid & 63, wv = tid >> 6;
    if (lane == 0) {
#pragma unroll
        for (int c = 0; c < NCLS; ++c) red[wv][c] = acc[c];
    }
    __syncthreads();
    if (tid < NCLS) {
        float v = red[0][tid] + red[1][tid] + red[2][tid] + red[3][tid];
        atomicAdd(out + b * NCLS + tid, v);
    }
}

// ---------------------------------------------------------------------------
extern "C" void kernel_launch(void* const* d_in, const int* in_sizes, int n_in,
                              void* d_out, int out_size, void* d_ws, size_t ws_size,
                              hipStream_t stream)
{
    const float* x     = (const float*)d_in[0];  // (32, 617)
    const float* id_w  = (const float*)d_in[1];  // (617, 10000)
    const float* lvl_w = (const float*)d_in[2];  // (100, 10000)
    const float* W     = (const float*)d_in[3];  // (26, 10000)
    float* out = (float*)d_out;                  // (32, 26)

    int*    offb = (int*)d_ws;
    __half* part = (__half*)((char*)d_ws + PART_OFF);

    // s-chunk count: 8 if ws allows (needs 128K + 8*32*10000*2 = 5.25 MB)
    int nch = MAXCHUNK;
    size_t avail = ws_size > PART_OFF ? ws_size - PART_OFF : 0;
    int maxch = (int)(avail / ((size_t)BATCH * DIMS * 2));
    if (maxch < 1) maxch = 1;
    if (nch > maxch) nch = maxch;
    int sPer = (SSIZE + nch - 1) / nch;

    k_prep<<<(BATCH * SSIZE + 255) / 256, 256, 0, stream>>>(x, offb, out);

    dim3 g2((DIMS + DTILE - 1) / DTILE, nch);   // (40, 8)
    k_bind<<<g2, 256, 0, stream>>>(id_w, lvl_w, offb, part, sPer);

    dim3 g3(BATCH, 5);                          // 160 blocks
    k_logit<<<g3, 256, 0, stream>>>(part, W, out, nch);
}

// Round 2
// 135.991 us; speedup vs baseline: 1.2445x; 1.2445x over previous
//
#include <hip/hip_runtime.h>
#include <hip/hip_fp16.h>

// Problem constants (from reference)
#define DIMS   10000
#define LEVELS 100
#define SSIZE  617
#define NCLS   26
#define BATCH  32

// Tiling
#define DTILE 256                 // dims per block (64 lanes x 4 dims, split 2+2)
#define TILE_PITCH_B (DTILE * 2)  // bytes per level row in LDS (fp16) = 512
#define MAXCHUNK 16

// ws layout: [0, 128K) int32 offsets off[s][b] = idx*512 ; part at 128 KiB
#define PART_OFF (128 * 1024)

// ---------------------------------------------------------------------------
// K1: quantize x -> level indices, pre-scaled to LDS byte offsets, stored
// TRANSPOSED off[s][b] so 8 consecutive b for fixed s merge into one
// s_load_dwordx8 in K2's inner loop. Also zero-init d_out (poisoned 0xAA).
// ---------------------------------------------------------------------------
__global__ __launch_bounds__(256) void k_prep(const float* __restrict__ x,
                                              int* __restrict__ offb,
                                              float* __restrict__ out)
{
    int tid = blockIdx.x * 256 + threadIdx.x;
    if (tid < BATCH * SSIZE) {
        int b = tid / SSIZE;
        int s = tid - b * SSIZE;
        float v = x[tid];                         // x[b][s]
        float r = rintf(v * (float)(LEVELS - 1)); // RTE, matches jnp.round
        int q = (int)r;
        q = q < 0 ? 0 : (q > LEVELS - 1 ? LEVELS - 1 : q);
        offb[s * BATCH + b] = q * TILE_PITCH_B;
    }
    if (tid < BATCH * NCLS) out[tid] = 0.0f;
}

// ---------------------------------------------------------------------------
// K2: bind + multiset partial sums.
// Block: 256 threads = 4 waves, all covering the same 256-dim tile; each wave
// owns 8 batches (template const B0 -> offset loads stay wave-uniform s_loads).
// Lane owns dims (d0+2*lane, +1) and (d0+128+2*lane, +1): LDS reads are
// lane-stride 4 B (2-way bank aliasing = free), mergeable to ds_read2_b32.
// s-loop unrolled x4 with hoisted loads -> 4 outstanding VMEM per wave.
// fp16 accumulation exact: products +-1, |sum| <= 617 < 2048.
// ---------------------------------------------------------------------------
template <int B0>
__device__ __forceinline__ void inner_loop(const float* __restrict__ id_w,
                                           const int* __restrict__ offb,
                                           const unsigned int* tile,
                                           __half* __restrict__ part,
                                           int d0, int lane, int chunk,
                                           int sBeg, int sEnd)
{
    const int dA = d0 + 2 * lane;
    const int dB = dA + 128;
    const bool vA = dA < DIMS;   // DIMS even -> pair all-or-none
    const bool vB = dB < DIMS;
    const __half2 z = __float2half2_rn(0.0f);
    __half2 a0[8], a1[8];
#pragma unroll
    for (int b = 0; b < 8; ++b) { a0[b] = z; a1[b] = z; }

    int s = sBeg;
    for (; s + 4 <= sEnd; s += 4) {
        float2 fA[4], fB[4];
        int off[4][8];
#pragma unroll
        for (int k = 0; k < 4; ++k) {
            const size_t row = (size_t)(s + k) * DIMS;
            fA[k] = vA ? *(const float2*)(id_w + row + dA) : make_float2(0.f, 0.f);
            fB[k] = vB ? *(const float2*)(id_w + row + dB) : make_float2(0.f, 0.f);
            const int* orow = offb + (s + k) * BATCH + B0;  // uniform -> s_load_dwordx8
#pragma unroll
            for (int b = 0; b < 8; ++b) off[k][b] = orow[b];
        }
#pragma unroll
        for (int k = 0; k < 4; ++k) {
            __half2 p0 = __float22half2_rn(fA[k]);
            __half2 p1 = __float22half2_rn(fB[k]);
#pragma unroll
            for (int b = 0; b < 8; ++b) {
                unsigned base = ((unsigned)off[k][b] >> 2) + lane;
                __half2 l0 = __builtin_bit_cast(__half2, tile[base]);
                __half2 l1 = __builtin_bit_cast(__half2, tile[base + 64]);
                a0[b] = __hfma2(p0, l0, a0[b]);
                a1[b] = __hfma2(p1, l1, a1[b]);
            }
        }
    }
    for (; s < sEnd; ++s) {  // tail (sPer % 4)
        const size_t row = (size_t)s * DIMS;
        float2 fA = vA ? *(const float2*)(id_w + row + dA) : make_float2(0.f, 0.f);
        float2 fB = vB ? *(const float2*)(id_w + row + dB) : make_float2(0.f, 0.f);
        const int* orow = offb + s * BATCH + B0;
        __half2 p0 = __float22half2_rn(fA);
        __half2 p1 = __float22half2_rn(fB);
#pragma unroll
        for (int b = 0; b < 8; ++b) {
            unsigned base = ((unsigned)orow[b] >> 2) + lane;
            __half2 l0 = __builtin_bit_cast(__half2, tile[base]);
            __half2 l1 = __builtin_bit_cast(__half2, tile[base + 64]);
            a0[b] = __hfma2(p0, l0, a0[b]);
            a1[b] = __hfma2(p1, l1, a1[b]);
        }
    }

#pragma unroll
    for (int b = 0; b < 8; ++b) {
        const size_t rb = (size_t)(chunk * BATCH + B0 + b) * DIMS;
        if (vA) *(unsigned int*)((char*)part + (rb + dA) * 2) =
            __builtin_bit_cast(unsigned int, a0[b]);
        if (vB) *(unsigned int*)((char*)part + (rb + dB) * 2) =
            __builtin_bit_cast(unsigned int, a1[b]);
    }
}

__global__ __launch_bounds__(256, 3) void k_bind(const float* __restrict__ id_w,
                                                 const float* __restrict__ lvl_w,
                                                 const int* __restrict__ offb,
                                                 __half* __restrict__ part,
                                                 int sPer)
{
    __shared__ unsigned int tile[LEVELS * (DTILE / 2)];  // 100*128 u32 = 50 KB
    const int d0 = blockIdx.x * DTILE;
    const int chunk = blockIdx.y;
    const int tid = threadIdx.x;

    // Stage level tile, converting fp32 -> packed fp16 on the fly.
    for (int t = tid; t < LEVELS * (DTILE / 2); t += 256) {
        int r = t >> 7;            // /128
        int j = t & 127;
        int d = d0 + 2 * j;
        int dc = d < DIMS ? d : 0; // clamp (values unused for invalid dims)
        float2 v = *(const float2*)(lvl_w + (size_t)r * DIMS + dc);
        __half2 h = __float22half2_rn(v);
        tile[t] = __builtin_bit_cast(unsigned int, h);
    }
    __syncthreads();

    const int wave = tid >> 6;
    const int lane = tid & 63;
    const int sBeg = chunk * sPer;
    const int sEnd = min(SSIZE, sBeg + sPer);
    if (sBeg >= sEnd) return;

    switch (wave) {
        case 0: inner_loop<0 >(id_w, offb, tile, part, d0, lane, chunk, sBeg, sEnd); break;
        case 1: inner_loop<8 >(id_w, offb, tile, part, d0, lane, chunk, sBeg, sEnd); break;
        case 2: inner_loop<16>(id_w, offb, tile, part, d0, lane, chunk, sBeg, sEnd); break;
        case 3: inner_loop<24>(id_w, offb, tile, part, d0, lane, chunk, sBeg, sEnd); break;
    }
}

// ---------------------------------------------------------------------------
// K3: reduce chunk partials, hard-quantize (sum of 617 odd +-1 terms is never
// 0, so no tie case), then logit[b][c] += enc . W[c]. Grid (32 b, 10 d-splits)
// wave-shuffle reduction, atomicAdd into the zeroed output.
// ---------------------------------------------------------------------------
__global__ __launch_bounds__(256) void k_logit(const __half* __restrict__ part,
                                               const float* __restrict__ W,
                                               float* __restrict__ out,
                                               int nch)
{
    const int b = blockIdx.x;
    const int tid = threadIdx.x;
    const int pBeg = blockIdx.y * 500;   // half2 pairs: 5000 total

    float acc[NCLS];
#pragma unroll
    for (int c = 0; c < NCLS; ++c) acc[c] = 0.0f;

    for (int p = pBeg + tid; p < pBeg + 500; p += 256) {
        const int d = 2 * p;
        float mx = 0.0f, my = 0.0f;
        for (int c = 0; c < nch; ++c) {
            __half2 h = *(const __half2*)(part + (size_t)(c * BATCH + b) * DIMS + d);
            float2 f = __half22float2(h);
            mx += f.x; my += f.y;
        }
        float e0 = mx > 0.0f ? 1.0f : -1.0f;
        float e1 = my > 0.0f ? 1.0f : -1.0f;
#pragma unroll
        for (int c = 0; c < NCLS; ++c) {
            float2 w = *(const float2*)(W + (size_t)c * DIMS + d);
            acc[c] = fmaf(e0, w.x, fmaf(e1, w.y, acc[c]));
        }
    }

#pragma unroll
    for (int c = 0; c < NCLS; ++c) {
#pragma unroll
        for (int o = 32; o > 0; o >>= 1)
            acc[c] += __shfl_down(acc[c], o);
    }

    __shared__ float red[4][NCLS];
    const int lane = tid & 63, wv = tid >> 6;
    if (lane == 0) {
#pragma unroll
        for (int c = 0; c < NCLS; ++c) red[wv][c] = acc[c];
    }
    __syncthreads();
    if (tid < NCLS) {
        float v = red[0][tid] + red[1][tid] + red[2][tid] + red[3][tid];
        atomicAdd(out + b * NCLS + tid, v);
    }
}

// ---------------------------------------------------------------------------
extern "C" void kernel_launch(void* const* d_in, const int* in_sizes, int n_in,
                              void* d_out, int out_size, void* d_ws, size_t ws_size,
                              hipStream_t stream)
{
    const float* x     = (const float*)d_in[0];  // (32, 617)
    const float* id_w  = (const float*)d_in[1];  // (617, 10000)
    const float* lvl_w = (const float*)d_in[2];  // (100, 10000)
    const float* W     = (const float*)d_in[3];  // (26, 10000)
    float* out = (float*)d_out;                  // (32, 26)

    int*    offb = (int*)d_ws;
    __half* part = (__half*)((char*)d_ws + PART_OFF);

    // s-chunk count: 16 if ws allows (needs 128K + 16*32*10000*2 = 10.4 MB)
    int nch = MAXCHUNK;
    size_t avail = ws_size > PART_OFF ? ws_size - PART_OFF : 0;
    int maxch = (int)(avail / ((size_t)BATCH * DIMS * 2));
    if (maxch < 1) maxch = 1;
    if (nch > maxch) nch = maxch;
    int sPer = (SSIZE + nch - 1) / nch;

    k_prep<<<(BATCH * SSIZE + 255) / 256, 256, 0, stream>>>(x, offb, out);

    dim3 g2((DIMS + DTILE - 1) / DTILE, nch);   // (40, 16)
    k_bind<<<g2, 256, 0, stream>>>(id_w, lvl_w, offb, part, sPer);

    dim3 g3(BATCH, 10);                         // 320 blocks
    k_logit<<<g3, 256, 0, stream>>>(part, W, out, nch);
}